// Round 1
// baseline (258.980 us; speedup 1.0000x reference)
//
#include <hip/hip_runtime.h>
#include <hip/hip_bf16.h>
#include <math.h>

constexpr int B_ = 16;
constexpr int T_ = 10240;
constexpr int C_ = 256;
constexpr int KW = 10;
constexpr int L_ = 2047;
constexpr int N_ = B_ * L_;      // 32752
constexpr int KSTEPS = 12;
constexpr float EPS_ = 1e-5f;
constexpr int QSTR = 32768;      // per-k stride of transposed q (2048*16)

typedef short bf16x8 __attribute__((ext_vector_type(8)));
typedef float f32x4  __attribute__((ext_vector_type(4)));
typedef float f32x16 __attribute__((ext_vector_type(16)));

// -------------------- fused: conv+relu+BN-stats  ∪  W-transpose --------------------
__global__ __launch_bounds__(256) void stats_wt_kernel(
    const float* __restrict__ x, const float* __restrict__ cw, const float* __restrict__ cb,
    float* __restrict__ ssum, float* __restrict__ ssq,
    const float* __restrict__ tw, __hip_bfloat16* __restrict__ Wt)
{
    __shared__ float smem[64 * 65];
    const int bid = blockIdx.x;
    if (bid < 256) {
        const int b  = bid & 15;
        const int l0 = (bid >> 4) * 128;
        const int cnt = min(128, L_ - l0);
        const int c = threadIdx.x;
        float* xs = smem;
        const float* xb = x + (size_t)b * T_;
        for (int i = threadIdx.x; i < cnt * 5 + 5; i += 256) xs[i] = xb[l0 * 5 + i];
        float w[KW];
#pragma unroll
        for (int j = 0; j < KW; ++j) w[j] = cw[c * KW + j];
        const float bias = cb[c];
        __syncthreads();
        float s = 0.f, s2 = 0.f;
        for (int dl = 0; dl < cnt; ++dl) {
            float v = bias;
#pragma unroll
            for (int j = 0; j < KW; ++j) v = fmaf(xs[dl * 5 + j], w[j], v);
            v = fmaxf(v, 0.f);
            s += v;
            s2 = fmaf(v, v, s2);
        }
        atomicAdd(&ssum[c], s);
        atomicAdd(&ssq[c], s2);
    } else {
        const int idx = bid - 256;            // 0..191
        const int k  = idx >> 4;
        const int c0 = ((idx & 15) >> 2) * 64, j0 = (idx & 3) * 64;
        float (*tile)[65] = (float(*)[65])smem;
        for (int i = threadIdx.x; i < 64 * 64; i += 256) {
            int c = i >> 6, j = i & 63;
            tile[c][j] = tw[((size_t)k * C_ + (c0 + c)) * C_ + j0 + j];
        }
        __syncthreads();
        for (int i = threadIdx.x; i < 64 * 64; i += 256) {
            int j = i >> 6, c = i & 63;
            Wt[((size_t)k * C_ + (j0 + j)) * C_ + c0 + c] = __float2bfloat16(tile[c][j]);
        }
    }
}

// -------------------- conv+relu+normalize (BN finalize fused) → out0 + Zb -----------
__global__ __launch_bounds__(256) void conv_norm_kernel(
    const float* __restrict__ x, const float* __restrict__ cw, const float* __restrict__ cb,
    const float* __restrict__ ssum, const float* __restrict__ ssq,
    const float* __restrict__ gamma, const float* __restrict__ beta,
    __hip_bfloat16* __restrict__ Zb, float* __restrict__ out0)
{
    const int b  = blockIdx.y;
    const int l0 = blockIdx.x * 32;
    const int cnt = min(32, L_ - l0);
    const int c = threadIdx.x;
    __shared__ float xs[32 * 5 + 8];
    __shared__ float zt[32][257];
    const float* xb = x + (size_t)b * T_;
    for (int i = threadIdx.x; i < cnt * 5 + 5; i += 256) xs[i] = xb[l0 * 5 + i];
    float w[KW];
#pragma unroll
    for (int j = 0; j < KW; ++j) w[j] = cw[c * KW + j];
    const float bias = cb[c];
    // BN finalize inline (stats complete via stream order)
    const float inv_n = 1.0f / (float)N_;
    const float mu  = ssum[c] * inv_n;
    const float var = ssq[c] * inv_n - mu * mu;
    const float sc  = gamma[c] * rsqrtf(var + EPS_);
    const float sh  = beta[c] - mu * sc;
    __syncthreads();
    for (int dl = 0; dl < cnt; ++dl) {
        float v = bias;
#pragma unroll
        for (int j = 0; j < KW; ++j) v = fmaf(xs[dl * 5 + j], w[j], v);
        v = fmaxf(v, 0.f);
        float z = fmaf(v, sc, sh);
        Zb[((size_t)(b * L_ + l0 + dl)) * C_ + c] = __float2bfloat16(z);
        zt[dl][c] = z;
    }
    __syncthreads();
    const int lq  = threadIdx.x & 31;
    const int cr0 = threadIdx.x >> 5;      // 0..7
    if (lq < cnt) {
#pragma unroll
        for (int i = 0; i < 32; ++i) {
            int cr = cr0 * 32 + i;
            out0[((size_t)(b * C_ + cr)) * L_ + l0 + lq] = zt[lq][cr];
        }
    }
}

// -------------------- q kernel: 32x32x16 MFMA, K-split waves, async staging ----------
// grid (128, 13), 512 threads (8 waves). k<12: wave = (cg = w&3 → 64 cols, kh = w>>2 →
// K-half of 128). wfrag 64 VGPR + acc 32 → fits 128 VGPR → 4 waves/SIMD (2 blocks/CU).
// q partial rowsums over K-halves add linearly in qacc. k==12: bias plane — computes
// qb_k[n] = sum_c tb[k][c] z[n][c] and atomicAdds into all 12 qt planes (loss unchanged).
// Staging: global_load_lds dwordx4, inverse-swizzled global src + linear LDS dest;
// double-buffered, counted vmcnt(2) (never 0 mid-loop).
__global__ __launch_bounds__(512, 4) void qmfma_kernel(
    const __hip_bfloat16* __restrict__ Zb, const __hip_bfloat16* __restrict__ Wt,
    const float* __restrict__ tb, float* __restrict__ qt)
{
    const int k   = blockIdx.y;            // 0..11 GEMM planes, 12 = bias plane
    const int grp = blockIdx.x;            // 256-row groups

    __shared__ __hip_bfloat16 zs[2][32 * 256];   // 32 rows x 512B, 16B chunk j at slot j^(r&7)
    __shared__ float qaccU[8 * 384];             // main: [w][256]; bias: [w][12][32]

    const int tid  = threadIdx.x;
    const int lane = tid & 63, wave = tid >> 6;
    const int n31  = lane & 31, h = lane >> 5;
    const int sw   = n31 & 7;
    const int row0 = grp * 256;

    // staging lane constants: instr i covers chunks wave*128 + i*64 + lane
    const int c0 = wave * 128 + lane;
    const int c1 = c0 + 64;
    const int r0_ = c0 >> 5; const int j0_ = (c0 & 31) ^ (r0_ & 7);
    const int r1_ = c1 >> 5; const int j1_ = (c1 & 31) ^ (r1_ & 7);

#define STAGE(buf, t) do {                                                                 \
    int rg0 = row0 + (t) * 32 + r0_; if (rg0 > N_ - 1) rg0 = N_ - 1;                       \
    int rg1 = row0 + (t) * 32 + r1_; if (rg1 > N_ - 1) rg1 = N_ - 1;                       \
    __builtin_amdgcn_global_load_lds(                                                      \
        (const __attribute__((address_space(1))) void*)(Zb + (size_t)rg0 * C_ + j0_ * 8),  \
        (__attribute__((address_space(3))) void*)(&zs[buf][wave * 1024]), 16, 0, 0);       \
    __builtin_amdgcn_global_load_lds(                                                      \
        (const __attribute__((address_space(1))) void*)(Zb + (size_t)rg1 * C_ + j1_ * 8),  \
        (__attribute__((address_space(3))) void*)(&zs[buf][wave * 1024 + 512]), 16, 0, 0); \
} while (0)

    if (k < KSTEPS) {
        const int cg = wave & 3, kh = wave >> 2;
        // A-frag: A[i=cout][kk]: cout = 64cg + 32ct + n31, kk = 128kh + it*16 + h*8 + e
        bf16x8 wfrag[2][8];
        {
            const __hip_bfloat16* wb =
                Wt + ((size_t)k * C_ + 64 * cg + n31) * C_ + 128 * kh + h * 8;
#pragma unroll
            for (int ct = 0; ct < 2; ++ct)
#pragma unroll
                for (int it = 0; it < 8; ++it)
                    wfrag[ct][it] = *(const bf16x8*)(wb + (size_t)ct * 32 * C_ + it * 16);
        }
        STAGE(0, 0);
        asm volatile("s_waitcnt vmcnt(0)" ::: "memory");
        __builtin_amdgcn_s_barrier();

        int p = 0;
        for (int t = 0; t < 8; ++t, p ^= 1) {
            if (t < 7) {
                STAGE(p ^ 1, t + 1);
                asm volatile("s_waitcnt vmcnt(2)" ::: "memory");
            } else {
                asm volatile("s_waitcnt vmcnt(0)" ::: "memory");
            }
            __builtin_amdgcn_s_barrier();

            const __hip_bfloat16* zsp = zs[p];
            f32x16 acc0, acc1;
#pragma unroll
            for (int i = 0; i < 16; ++i) { acc0[i] = 0.f; acc1[i] = 0.f; }
#pragma unroll
            for (int it = 0; it < 8; ++it) {
                const int chunk = kh * 16 + it * 2 + h;  // B[kk][n31]
                bf16x8 zf = *(const bf16x8*)(zsp + n31 * 256 + ((chunk ^ sw) * 8));
                acc0 = __builtin_amdgcn_mfma_f32_32x32x16_bf16(wfrag[0][it], zf, acc0, 0, 0, 0);
                acc1 = __builtin_amdgcn_mfma_f32_32x32x16_bf16(wfrag[1][it], zf, acc1, 0, 0, 0);
            }
            // epilogue: s = sum over lane's 32 Y entries * z ; c = 64cg+32ct+ (reg&3)+8(reg>>2)+4h
            float s = 0.f;
#pragma unroll
            for (int ct = 0; ct < 2; ++ct) {
#pragma unroll
                for (int g2 = 0; g2 < 4; ++g2) {
                    const int chunk = 8 * cg + 4 * ct + g2;
                    const char* zp = (const char*)zsp + n31 * 512 + ((chunk ^ sw) << 4) + 8 * h;
                    uint2 zz = *(const uint2*)zp;
                    float z0 = __uint_as_float(zz.x << 16);
                    float z1 = __uint_as_float(zz.x & 0xffff0000u);
                    float z2 = __uint_as_float(zz.y << 16);
                    float z3 = __uint_as_float(zz.y & 0xffff0000u);
                    const f32x16& a = ct ? acc1 : acc0;
                    s = fmaf(a[g2 * 4 + 0], z0, s);
                    s = fmaf(a[g2 * 4 + 1], z1, s);
                    s = fmaf(a[g2 * 4 + 2], z2, s);
                    s = fmaf(a[g2 * 4 + 3], z3, s);
                }
            }
            s += __shfl_xor(s, 32);
            if (lane < 32) qaccU[wave * 256 + t * 32 + n31] = s;
            asm volatile("s_waitcnt lgkmcnt(0)" ::: "memory");
            __builtin_amdgcn_s_barrier();
        }
        // final: reduce 8 wave partials per row, atomic into plane k
        if (tid < 256) {
            int rg = row0 + tid;
            if (rg < N_) {
                float qv = 0.f;
#pragma unroll
                for (int w2 = 0; w2 < 8; ++w2) qv += qaccU[w2 * 256 + tid];
                int b = rg / L_;
                int l = rg - b * L_;
                atomicAdd(&qt[(size_t)k * QSTR + (l << 4) + b], qv);
            }
        }
    } else {
        // ---- bias plane: wave owns c = 32*wave + 8g2 + 4h + r ; adds qb_k to all planes
        STAGE(0, 0);
        asm volatile("s_waitcnt vmcnt(0)" ::: "memory");
        __builtin_amdgcn_s_barrier();

        int p = 0;
        for (int t = 0; t < 8; ++t, p ^= 1) {
            if (t < 7) {
                STAGE(p ^ 1, t + 1);
                asm volatile("s_waitcnt vmcnt(2)" ::: "memory");
            } else {
                asm volatile("s_waitcnt vmcnt(0)" ::: "memory");
            }
            __builtin_amdgcn_s_barrier();

            const __hip_bfloat16* zsp = zs[p];
            float zv[16];
#pragma unroll
            for (int g2 = 0; g2 < 4; ++g2) {
                const int chunk = 4 * wave + g2;
                const char* zp = (const char*)zsp + n31 * 512 + ((chunk ^ sw) << 4) + 8 * h;
                uint2 zz = *(const uint2*)zp;
                zv[g2 * 4 + 0] = __uint_as_float(zz.x << 16);
                zv[g2 * 4 + 1] = __uint_as_float(zz.x & 0xffff0000u);
                zv[g2 * 4 + 2] = __uint_as_float(zz.y << 16);
                zv[g2 * 4 + 3] = __uint_as_float(zz.y & 0xffff0000u);
            }
#pragma unroll
            for (int kk = 0; kk < KSTEPS; ++kk) {
                float sk = 0.f;
#pragma unroll
                for (int g2 = 0; g2 < 4; ++g2) {
                    float4 b4 = *(const float4*)(tb + kk * C_ + 32 * wave + 8 * g2 + 4 * h);
                    sk = fmaf(b4.x, zv[g2 * 4 + 0], sk);
                    sk = fmaf(b4.y, zv[g2 * 4 + 1], sk);
                    sk = fmaf(b4.z, zv[g2 * 4 + 2], sk);
                    sk = fmaf(b4.w, zv[g2 * 4 + 3], sk);
                }
                sk += __shfl_xor(sk, 32);
                if (lane < 32) qaccU[wave * 384 + kk * 32 + n31] = sk;
            }
            asm volatile("s_waitcnt lgkmcnt(0)" ::: "memory");
            __builtin_amdgcn_s_barrier();
            // per-tile reduce + atomic into all 12 planes (reads pre-next-B1, writes post-B1: safe)
            if (tid < 384) {
                int kk = tid >> 5, row = tid & 31;
                int rg = row0 + t * 32 + row;
                if (rg < N_) {
                    float qv = 0.f;
#pragma unroll
                    for (int w2 = 0; w2 < 8; ++w2) qv += qaccU[w2 * 384 + kk * 32 + row];
                    int b = rg / L_;
                    int l = rg - b * L_;
                    atomicAdd(&qt[(size_t)kk * QSTR + (l << 4) + b], qv);
                }
            }
        }
    }
#undef STAGE
}

// -------------------- loss: coalesced gathers from transposed q, LSE, accumulate ------
__global__ __launch_bounds__(256) void loss_kernel(
    const float* __restrict__ qt, const int* __restrict__ perm, float* __restrict__ lacc)
{
    const int k = blockIdx.y + 1;                 // 1..12
    const float* qk = qt + (size_t)(k - 1) * QSTR;
    const int nval = B_ * (L_ - k);
    const int idx = blockIdx.x * 256 + threadIdx.x;

    float contrib = 0.f;
    if (idx < nval) {
        int b = idx & 15;
        int l = k + (idx >> 4);
        float f0 = qk[(l << 4) | b];
        int pl = perm[l];
        const float* qn = qk + ((size_t)pl << 4);
        float f[10];
#pragma unroll
        for (int n = 0; n < 10; ++n) f[n] = qn[(b + 15 - n) & 15];
        float m = f0;
#pragma unroll
        for (int i = 0; i < 10; ++i) m = fmaxf(m, f[i]);
        float se = expf(f0 - m), fs = f0;
#pragma unroll
        for (int i = 0; i < 10; ++i) { se += expf(f[i] - m); fs += f[i]; }
        contrib = 11.f * (m + logf(se)) - fs;
    }

    __shared__ float red[4];
#pragma unroll
    for (int off = 32; off > 0; off >>= 1) contrib += __shfl_down(contrib, off);
    const int lane = threadIdx.x & 63;
    const int wave = threadIdx.x >> 6;
    if (lane == 0) red[wave] = contrib;
    __syncthreads();
    if (threadIdx.x == 0) atomicAdd(&lacc[k - 1], red[0] + red[1] + red[2] + red[3]);
}

__global__ void finalize_loss_kernel(const float* __restrict__ lacc, float* __restrict__ out1)
{
    int k = threadIdx.x;
    if (k < KSTEPS) {
        float div = (float)((L_ - 2 * (k + 1)) * B_);
        out1[k] = lacc[k] / div;
    }
}

// -------------------- launch --------------------
extern "C" void kernel_launch(void* const* d_in, const int* in_sizes, int n_in,
                              void* d_out, int out_size, void* d_ws, size_t ws_size,
                              hipStream_t stream)
{
    const float* x     = (const float*)d_in[0];
    const float* cw    = (const float*)d_in[1];
    const float* cb    = (const float*)d_in[2];
    const float* gamma = (const float*)d_in[3];
    const float* beta  = (const float*)d_in[4];
    const float* tw    = (const float*)d_in[5];
    const float* tb    = (const float*)d_in[6];
    const int*   perm  = (const int*)d_in[7];

    float* out0 = (float*)d_out;
    float* out1 = out0 + (size_t)B_ * C_ * L_;

    char* ws = (char*)d_ws;
    float* qt   = (float*)ws;                   ws += (size_t)KSTEPS * QSTR * 4;
    float* ssum = (float*)ws;                   ws += C_ * 4;
    float* ssq  = (float*)ws;                   ws += C_ * 4;
    float* lacc = (float*)ws;                   ws += 64 * 4;
    __hip_bfloat16* Zb = (__hip_bfloat16*)ws;   ws += (size_t)N_ * C_ * 2;
    __hip_bfloat16* Wt = (__hip_bfloat16*)ws;   ws += (size_t)KSTEPS * C_ * C_ * 2;

    // zero qt (atomic-accumulated) + ssum + ssq + lacc in one contiguous memset
    hipMemsetAsync(qt, 0, (size_t)(KSTEPS * QSTR + C_ + C_ + 64) * sizeof(float), stream);

    stats_wt_kernel<<<448, 256, 0, stream>>>(x, cw, cb, ssum, ssq, tw, Wt);

    dim3 gcv(64, 16);
    conv_norm_kernel<<<gcv, 256, 0, stream>>>(x, cw, cb, ssum, ssq, gamma, beta, Zb, out0);

    dim3 gq(128, KSTEPS + 1);
    qmfma_kernel<<<gq, 512, 0, stream>>>(Zb, Wt, tb, qt);

    dim3 gl(128, KSTEPS);
    loss_kernel<<<gl, 256, 0, stream>>>(qt, perm, lacc);
    finalize_loss_kernel<<<1, 64, 0, stream>>>(lacc, out1);
}

// Round 2
// 190.337 us; speedup vs baseline: 1.3606x; 1.3606x over previous
//
#include <hip/hip_runtime.h>
#include <hip/hip_bf16.h>
#include <math.h>

constexpr int B_ = 16;
constexpr int T_ = 10240;
constexpr int C_ = 256;
constexpr int KW = 10;
constexpr int L_ = 2047;
constexpr int N_ = B_ * L_;      // 32752
constexpr int KSTEPS = 12;
constexpr float EPS_ = 1e-5f;
constexpr int QSTR = 32768;      // per-k stride of transposed q (2048*16)

typedef short bf16x8 __attribute__((ext_vector_type(8)));
typedef float f32x4  __attribute__((ext_vector_type(4)));

// -------------------- fused: conv+relu+BN-stats  ∪  W-transpose --------------------
__global__ __launch_bounds__(256) void stats_wt_kernel(
    const float* __restrict__ x, const float* __restrict__ cw, const float* __restrict__ cb,
    float* __restrict__ ssum, float* __restrict__ ssq,
    const float* __restrict__ tw, __hip_bfloat16* __restrict__ Wt)
{
    __shared__ float smem[64 * 65];
    const int bid = blockIdx.x;
    if (bid < 256) {
        const int b  = bid & 15;
        const int l0 = (bid >> 4) * 128;
        const int cnt = min(128, L_ - l0);
        const int c = threadIdx.x;
        float* xs = smem;
        const float* xb = x + (size_t)b * T_;
        for (int i = threadIdx.x; i < cnt * 5 + 5; i += 256) xs[i] = xb[l0 * 5 + i];
        float w[KW];
#pragma unroll
        for (int j = 0; j < KW; ++j) w[j] = cw[c * KW + j];
        const float bias = cb[c];
        __syncthreads();
        float s = 0.f, s2 = 0.f;
        for (int dl = 0; dl < cnt; ++dl) {
            float v = bias;
#pragma unroll
            for (int j = 0; j < KW; ++j) v = fmaf(xs[dl * 5 + j], w[j], v);
            v = fmaxf(v, 0.f);
            s += v;
            s2 = fmaf(v, v, s2);
        }
        atomicAdd(&ssum[c], s);
        atomicAdd(&ssq[c], s2);
    } else {
        const int idx = bid - 256;            // 0..191
        const int k  = idx >> 4;
        const int c0 = ((idx & 15) >> 2) * 64, j0 = (idx & 3) * 64;
        float (*tile)[65] = (float(*)[65])smem;
        for (int i = threadIdx.x; i < 64 * 64; i += 256) {
            int c = i >> 6, j = i & 63;
            tile[c][j] = tw[((size_t)k * C_ + (c0 + c)) * C_ + j0 + j];
        }
        __syncthreads();
        for (int i = threadIdx.x; i < 64 * 64; i += 256) {
            int j = i >> 6, c = i & 63;
            Wt[((size_t)k * C_ + (j0 + j)) * C_ + c0 + c] = __float2bfloat16(tile[c][j]);
        }
    }
}

// -------------------- conv+relu+normalize (BN finalize fused) → out0 + Zb -----------
__global__ __launch_bounds__(256) void conv_norm_kernel(
    const float* __restrict__ x, const float* __restrict__ cw, const float* __restrict__ cb,
    const float* __restrict__ ssum, const float* __restrict__ ssq,
    const float* __restrict__ gamma, const float* __restrict__ beta,
    __hip_bfloat16* __restrict__ Zb, float* __restrict__ out0)
{
    const int b  = blockIdx.y;
    const int l0 = blockIdx.x * 32;
    const int cnt = min(32, L_ - l0);
    const int c = threadIdx.x;
    __shared__ float xs[32 * 5 + 8];
    __shared__ float zt[32][257];
    const float* xb = x + (size_t)b * T_;
    for (int i = threadIdx.x; i < cnt * 5 + 5; i += 256) xs[i] = xb[l0 * 5 + i];
    float w[KW];
#pragma unroll
    for (int j = 0; j < KW; ++j) w[j] = cw[c * KW + j];
    const float bias = cb[c];
    const float inv_n = 1.0f / (float)N_;
    const float mu  = ssum[c] * inv_n;
    const float var = ssq[c] * inv_n - mu * mu;
    const float sc  = gamma[c] * rsqrtf(var + EPS_);
    const float sh  = beta[c] - mu * sc;
    __syncthreads();
    for (int dl = 0; dl < cnt; ++dl) {
        float v = bias;
#pragma unroll
        for (int j = 0; j < KW; ++j) v = fmaf(xs[dl * 5 + j], w[j], v);
        v = fmaxf(v, 0.f);
        float z = fmaf(v, sc, sh);
        Zb[((size_t)(b * L_ + l0 + dl)) * C_ + c] = __float2bfloat16(z);
        zt[dl][c] = z;
    }
    __syncthreads();
    const int lq  = threadIdx.x & 31;
    const int cr0 = threadIdx.x >> 5;      // 0..7
    if (lq < cnt) {
#pragma unroll
        for (int i = 0; i < 32; ++i) {
            int cr = cr0 * 32 + i;
            out0[((size_t)(b * C_ + cr)) * L_ + l0 + lq] = zt[lq][cr];
        }
    }
}

// -------------------- q kernel: round-0 structure + T3/T4/T5 staging ----------------
// 4 waves x 64 cols, wfrag[4][8] resident (128 VGPR), 16x16x32 MFMA, proven epilogue.
// Staging: global_load_lds dwordx4 (inverse-swizzled source, linear LDS dest) into a
// 4-buffer ring, 2-deep prefetch, counted vmcnt(8) (never 0 mid-loop), ONE raw
// s_barrier per tile (no mid-loop full drain), setprio(1) around the MFMA cluster.
__global__ __launch_bounds__(256, 2) void qmfma_kernel(
    const __hip_bfloat16* __restrict__ Zb, const __hip_bfloat16* __restrict__ Wt,
    const float* __restrict__ tb, float* __restrict__ qt)
{
    const int k   = blockIdx.y;
    const int grp = blockIdx.x;
    const __hip_bfloat16* __restrict__ Wk = Wt + (size_t)k * C_ * C_;

    __shared__ __hip_bfloat16 zs[4][32 * 256];   // 16B chunk j of row r at slot j^(r&7)
    __shared__ float qacc[4][256];

    const int tid  = threadIdx.x;
    const int lane = tid & 63, wave = tid >> 6;
    const int n16  = lane & 15, quad = lane >> 4;
    const int sw   = n16 & 7;
    const int row0 = grp * 8 * 32;

    // ---- W resident: col = 64*wave + ct*16 + n16 ; kk = it*32 + quad*8 + j ----
    bf16x8 wfrag[4][8];
    {
        const __hip_bfloat16* wb = Wk + ((size_t)(64 * wave + n16)) * C_ + quad * 8;
#pragma unroll
        for (int ct = 0; ct < 4; ++ct)
#pragma unroll
            for (int it = 0; it < 8; ++it)
                wfrag[ct][it] = *(const bf16x8*)(wb + ct * 16 * C_ + it * 32);
    }
    float4 bias4[4];
#pragma unroll
    for (int ct = 0; ct < 4; ++ct)
        bias4[ct] = *(const float4*)(tb + k * C_ + 64 * wave + ct * 16 + quad * 4);

    // staging: per wave 4 instrs; instr i covers rows (wave*4+i)*2+{0,1}, all 32 chunks
#define STAGE(buf, t) do {                                                                  \
    _Pragma("unroll")                                                                       \
    for (int i_ = 0; i_ < 4; ++i_) {                                                        \
        int rr = (wave * 4 + i_) * 2 + (lane >> 5);                                         \
        int rg = row0 + (t) * 32 + rr; if (rg > N_ - 1) rg = N_ - 1;                        \
        int jj = (lane & 31) ^ (rr & 7);                                                    \
        __builtin_amdgcn_global_load_lds(                                                   \
            (const __attribute__((address_space(1))) void*)(Zb + (size_t)rg * C_ + jj * 8), \
            (__attribute__((address_space(3))) void*)(&zs[buf][(wave * 4 + i_) * 512]),     \
            16, 0, 0);                                                                      \
    }                                                                                       \
} while (0)

    // prologue: stage tiles 0 and 1, drain once (also drains wfrag/bias loads)
    STAGE(0, 0);
    STAGE(1, 1);
    asm volatile("s_waitcnt vmcnt(0)" ::: "memory");

#pragma unroll
    for (int t = 0; t < 8; ++t) {
        if (t < 6) STAGE((t + 2) & 3, t + 2);
        if (t >= 2 && t < 6)      { asm volatile("s_waitcnt vmcnt(8)" ::: "memory"); }
        else if (t == 6)          { asm volatile("s_waitcnt vmcnt(4)" ::: "memory"); }
        else if (t == 7)          { asm volatile("s_waitcnt vmcnt(0)" ::: "memory"); }
        __builtin_amdgcn_s_barrier();

        const __hip_bfloat16* zsp = (const __hip_bfloat16*)zs[t & 3];

        f32x4 acc[2][4];
#pragma unroll
        for (int rt = 0; rt < 2; ++rt)
#pragma unroll
            for (int ct = 0; ct < 4; ++ct) acc[rt][ct] = f32x4{0.f, 0.f, 0.f, 0.f};

        __builtin_amdgcn_s_setprio(1);
#pragma unroll
        for (int it = 0; it < 8; ++it) {
            const int js = (it * 4 + quad) ^ sw;
            bf16x8 zf0 = *(const bf16x8*)(zsp + n16 * 256 + js * 8);
            bf16x8 zf1 = *(const bf16x8*)(zsp + (n16 + 16) * 256 + js * 8);
#pragma unroll
            for (int ct = 0; ct < 4; ++ct) {
                acc[0][ct] = __builtin_amdgcn_mfma_f32_16x16x32_bf16(
                    wfrag[ct][it], zf0, acc[0][ct], 0, 0, 0);
                acc[1][ct] = __builtin_amdgcn_mfma_f32_16x16x32_bf16(
                    wfrag[ct][it], zf1, acc[1][ct], 0, 0, 0);
            }
        }
        __builtin_amdgcn_s_setprio(0);

        // ---- epilogue: zrow = rt*16+n16 ; wcols = 64w + ct*16 + quad*4 + r ----
#pragma unroll
        for (int rt = 0; rt < 2; ++rt) {
            const int row = rt * 16 + n16;
            float s = 0.f;
#pragma unroll
            for (int ct = 0; ct < 4; ++ct) {
                const int j  = 8 * wave + 2 * ct + (quad >> 1);
                const char* zp = (const char*)zsp + row * 512 + ((j ^ sw) << 4) + (quad & 1) * 8;
                uint2 zz = *(const uint2*)zp;
                float z0 = __uint_as_float(zz.x << 16);
                float z1 = __uint_as_float(zz.x & 0xffff0000u);
                float z2 = __uint_as_float(zz.y << 16);
                float z3 = __uint_as_float(zz.y & 0xffff0000u);
                s = fmaf(acc[rt][ct][0] + bias4[ct].x, z0, s);
                s = fmaf(acc[rt][ct][1] + bias4[ct].y, z1, s);
                s = fmaf(acc[rt][ct][2] + bias4[ct].z, z2, s);
                s = fmaf(acc[rt][ct][3] + bias4[ct].w, z3, s);
            }
            s += __shfl_xor(s, 16);
            s += __shfl_xor(s, 32);
            if (lane < 16) qacc[wave][t * 32 + row] = s;   // wave-private slice
        }
        // no end-of-tile barrier: buffer t&3 is next overwritten at iter t+2,
        // separated by the top barrier of iter t+1.
    }
#undef STAGE

    __syncthreads();
    // ---- block-end: reduce 4 wave partials per row, write transposed qt ----
    {
        int r  = tid;
        int rg = row0 + r;
        if (rg < N_) {
            float qv = qacc[0][r] + qacc[1][r] + qacc[2][r] + qacc[3][r];
            int b = rg / L_;
            int l = rg - b * L_;
            qt[(size_t)k * QSTR + (l << 4) + b] = qv;
        }
    }
}

// -------------------- loss: coalesced gathers from transposed q, LSE, accumulate ------
__global__ __launch_bounds__(256) void loss_kernel(
    const float* __restrict__ qt, const int* __restrict__ perm, float* __restrict__ lacc)
{
    const int k = blockIdx.y + 1;                 // 1..12
    const float* qk = qt + (size_t)(k - 1) * QSTR;
    const int nval = B_ * (L_ - k);
    const int idx = blockIdx.x * 256 + threadIdx.x;

    float contrib = 0.f;
    if (idx < nval) {
        int b = idx & 15;
        int l = k + (idx >> 4);
        float f0 = qk[(l << 4) | b];
        int pl = perm[l];
        const float* qn = qk + ((size_t)pl << 4);
        float f[10];
#pragma unroll
        for (int n = 0; n < 10; ++n) f[n] = qn[(b + 15 - n) & 15];
        float m = f0;
#pragma unroll
        for (int i = 0; i < 10; ++i) m = fmaxf(m, f[i]);
        float se = expf(f0 - m), fs = f0;
#pragma unroll
        for (int i = 0; i < 10; ++i) { se += expf(f[i] - m); fs += f[i]; }
        contrib = 11.f * (m + logf(se)) - fs;
    }

    __shared__ float red[4];
#pragma unroll
    for (int off = 32; off > 0; off >>= 1) contrib += __shfl_down(contrib, off);
    const int lane = threadIdx.x & 63;
    const int wave = threadIdx.x >> 6;
    if (lane == 0) red[wave] = contrib;
    __syncthreads();
    if (threadIdx.x == 0) atomicAdd(&lacc[k - 1], red[0] + red[1] + red[2] + red[3]);
}

__global__ void finalize_loss_kernel(const float* __restrict__ lacc, float* __restrict__ out1)
{
    int k = threadIdx.x;
    if (k < KSTEPS) {
        float div = (float)((L_ - 2 * (k + 1)) * B_);
        out1[k] = lacc[k] / div;
    }
}

// -------------------- launch --------------------
extern "C" void kernel_launch(void* const* d_in, const int* in_sizes, int n_in,
                              void* d_out, int out_size, void* d_ws, size_t ws_size,
                              hipStream_t stream)
{
    const float* x     = (const float*)d_in[0];
    const float* cw    = (const float*)d_in[1];
    const float* cb    = (const float*)d_in[2];
    const float* gamma = (const float*)d_in[3];
    const float* beta  = (const float*)d_in[4];
    const float* tw    = (const float*)d_in[5];
    const float* tb    = (const float*)d_in[6];
    const int*   perm  = (const int*)d_in[7];

    float* out0 = (float*)d_out;
    float* out1 = out0 + (size_t)B_ * C_ * L_;

    char* ws = (char*)d_ws;
    __hip_bfloat16* Zb = (__hip_bfloat16*)ws;   ws += (size_t)N_ * C_ * 2;
    __hip_bfloat16* Wt = (__hip_bfloat16*)ws;   ws += (size_t)KSTEPS * C_ * C_ * 2;
    float* qt    = (float*)ws;                  ws += (size_t)KSTEPS * QSTR * 4;
    float* ssum  = (float*)ws;                  ws += C_ * 4;
    float* ssq   = (float*)ws;                  ws += C_ * 4;
    float* lacc  = (float*)ws;                  ws += 64 * 4;

    hipMemsetAsync(ssum, 0, (C_ + C_ + 64) * sizeof(float), stream);

    stats_wt_kernel<<<448, 256, 0, stream>>>(x, cw, cb, ssum, ssq, tw, Wt);

    dim3 gcv(64, 16);
    conv_norm_kernel<<<gcv, 256, 0, stream>>>(x, cw, cb, ssum, ssq, gamma, beta, Zb, out0);

    dim3 gq(128, KSTEPS);
    qmfma_kernel<<<gq, 256, 0, stream>>>(Zb, Wt, tb, qt);

    dim3 gl(128, KSTEPS);
    loss_kernel<<<gl, 256, 0, stream>>>(qt, perm, lacc);
    finalize_loss_kernel<<<1, 64, 0, stream>>>(lacc, out1);
}

// Round 3
// 185.338 us; speedup vs baseline: 1.3973x; 1.0270x over previous
//
#include <hip/hip_runtime.h>
#include <hip/hip_bf16.h>
#include <math.h>

constexpr int B_ = 16;
constexpr int T_ = 10240;
constexpr int C_ = 256;
constexpr int KW = 10;
constexpr int L_ = 2047;
constexpr int N_ = B_ * L_;      // 32752
constexpr int KSTEPS = 12;
constexpr float EPS_ = 1e-5f;
constexpr int QSTR = 32768;      // per-k stride of transposed q (2048*16)

typedef short bf16x8 __attribute__((ext_vector_type(8)));
typedef float f32x4  __attribute__((ext_vector_type(4)));

// -------------------- fused: conv+relu+BN-stats  ∪  W-transpose --------------------
__global__ __launch_bounds__(256) void stats_wt_kernel(
    const float* __restrict__ x, const float* __restrict__ cw, const float* __restrict__ cb,
    float* __restrict__ ssum, float* __restrict__ ssq,
    const float* __restrict__ tw, __hip_bfloat16* __restrict__ Wt)
{
    __shared__ float smem[64 * 65];
    const int bid = blockIdx.x;
    if (bid < 256) {
        const int b  = bid & 15;
        const int l0 = (bid >> 4) * 128;
        const int cnt = min(128, L_ - l0);
        const int c = threadIdx.x;
        float* xs = smem;
        const float* xb = x + (size_t)b * T_;
        for (int i = threadIdx.x; i < cnt * 5 + 5; i += 256) xs[i] = xb[l0 * 5 + i];
        float w[KW];
#pragma unroll
        for (int j = 0; j < KW; ++j) w[j] = cw[c * KW + j];
        const float bias = cb[c];
        __syncthreads();
        float s = 0.f, s2 = 0.f;
        for (int dl = 0; dl < cnt; ++dl) {
            float v = bias;
#pragma unroll
            for (int j = 0; j < KW; ++j) v = fmaf(xs[dl * 5 + j], w[j], v);
            v = fmaxf(v, 0.f);
            s += v;
            s2 = fmaf(v, v, s2);
        }
        atomicAdd(&ssum[c], s);
        atomicAdd(&ssq[c], s2);
    } else {
        const int idx = bid - 256;            // 0..191
        const int k  = idx >> 4;
        const int c0 = ((idx & 15) >> 2) * 64, j0 = (idx & 3) * 64;
        float (*tile)[65] = (float(*)[65])smem;
        for (int i = threadIdx.x; i < 64 * 64; i += 256) {
            int c = i >> 6, j = i & 63;
            tile[c][j] = tw[((size_t)k * C_ + (c0 + c)) * C_ + j0 + j];
        }
        __syncthreads();
        for (int i = threadIdx.x; i < 64 * 64; i += 256) {
            int j = i >> 6, c = i & 63;
            Wt[((size_t)k * C_ + (j0 + j)) * C_ + c0 + c] = __float2bfloat16(tile[c][j]);
        }
    }
}

// -------------------- conv+relu+normalize (BN finalize fused) → out0 + Zb -----------
__global__ __launch_bounds__(256) void conv_norm_kernel(
    const float* __restrict__ x, const float* __restrict__ cw, const float* __restrict__ cb,
    const float* __restrict__ ssum, const float* __restrict__ ssq,
    const float* __restrict__ gamma, const float* __restrict__ beta,
    __hip_bfloat16* __restrict__ Zb, float* __restrict__ out0)
{
    const int b  = blockIdx.y;
    const int l0 = blockIdx.x * 32;
    const int cnt = min(32, L_ - l0);
    const int c = threadIdx.x;
    __shared__ float xs[32 * 5 + 8];
    __shared__ float zt[32][257];
    const float* xb = x + (size_t)b * T_;
    for (int i = threadIdx.x; i < cnt * 5 + 5; i += 256) xs[i] = xb[l0 * 5 + i];
    float w[KW];
#pragma unroll
    for (int j = 0; j < KW; ++j) w[j] = cw[c * KW + j];
    const float bias = cb[c];
    const float inv_n = 1.0f / (float)N_;
    const float mu  = ssum[c] * inv_n;
    const float var = ssq[c] * inv_n - mu * mu;
    const float sc  = gamma[c] * rsqrtf(var + EPS_);
    const float sh  = beta[c] - mu * sc;
    __syncthreads();
    for (int dl = 0; dl < cnt; ++dl) {
        float v = bias;
#pragma unroll
        for (int j = 0; j < KW; ++j) v = fmaf(xs[dl * 5 + j], w[j], v);
        v = fmaxf(v, 0.f);
        float z = fmaf(v, sc, sh);
        Zb[((size_t)(b * L_ + l0 + dl)) * C_ + c] = __float2bfloat16(z);
        zt[dl][c] = z;
    }
    __syncthreads();
    const int lq  = threadIdx.x & 31;
    const int cr0 = threadIdx.x >> 5;      // 0..7
    if (lq < cnt) {
#pragma unroll
        for (int i = 0; i < 32; ++i) {
            int cr = cr0 * 32 + i;
            out0[((size_t)(b * C_ + cr)) * L_ + l0 + lq] = zt[lq][cr];
        }
    }
}

// -------------------- q kernel: 8 waves x 32 cols → 4 waves/SIMD occupancy ----------
// 512 threads, wave owns 32 W-cols (wfrag[2][8] = 64 VGPR, acc 16, bias 8 → ~120 regs,
// __launch_bounds__(512,4) pins ≤128 → 2 blocks/CU = 4 waves/SIMD, double round-2 TLP).
// Staging: global_load_lds dwordx4 (inverse-swizzled src, linear LDS dest), 4-buffer
// ring, 2-deep prefetch, counted vmcnt (never 0 mid-loop), one s_barrier per tile.
__global__ __launch_bounds__(512, 4) void qmfma_kernel(
    const __hip_bfloat16* __restrict__ Zb, const __hip_bfloat16* __restrict__ Wt,
    const float* __restrict__ tb, float* __restrict__ qt)
{
    const int k   = blockIdx.y;
    const int grp = blockIdx.x;
    const __hip_bfloat16* __restrict__ Wk = Wt + (size_t)k * C_ * C_;

    __shared__ __hip_bfloat16 zs[4][32 * 256];   // 16B chunk j of row r at slot j^(r&7)
    __shared__ float qacc[8][256];

    const int tid  = threadIdx.x;
    const int lane = tid & 63, wave = tid >> 6;   // wave 0..7
    const int n16  = lane & 15, quad = lane >> 4;
    const int sw   = n16 & 7;
    const int row0 = grp * 8 * 32;

    // ---- W resident: col = 32*wave + ct*16 + n16 ; kk = it*32 + quad*8 + j ----
    bf16x8 wfrag[2][8];
    {
        const __hip_bfloat16* wb = Wk + ((size_t)(32 * wave + n16)) * C_ + quad * 8;
#pragma unroll
        for (int ct = 0; ct < 2; ++ct)
#pragma unroll
            for (int it = 0; it < 8; ++it)
                wfrag[ct][it] = *(const bf16x8*)(wb + ct * 16 * C_ + it * 32);
    }
    float4 bias4[2];
#pragma unroll
    for (int ct = 0; ct < 2; ++ct)
        bias4[ct] = *(const float4*)(tb + k * C_ + 32 * wave + ct * 16 + quad * 4);

    // staging: per wave 2 instrs; instr i covers chunks i*512 + wave*64 + lane
#define STAGE(buf, t) do {                                                                  \
    _Pragma("unroll")                                                                       \
    for (int i_ = 0; i_ < 2; ++i_) {                                                        \
        int ch = i_ * 512 + wave * 64 + lane;                                               \
        int rr = ch >> 5;                                                                   \
        int rg = row0 + (t) * 32 + rr; if (rg > N_ - 1) rg = N_ - 1;                        \
        int jj = (lane & 31) ^ (rr & 7);                                                    \
        __builtin_amdgcn_global_load_lds(                                                   \
            (const __attribute__((address_space(1))) void*)(Zb + (size_t)rg * C_ + jj * 8), \
            (__attribute__((address_space(3))) void*)(&zs[buf][i_ * 4096 + wave * 512]),    \
            16, 0, 0);                                                                      \
    }                                                                                       \
} while (0)

    // prologue: stage tiles 0 and 1, drain once (also drains wfrag/bias loads)
    STAGE(0, 0);
    STAGE(1, 1);
    asm volatile("s_waitcnt vmcnt(0)" ::: "memory");

#pragma unroll
    for (int t = 0; t < 8; ++t) {
        if (t < 6) STAGE((t + 2) & 3, t + 2);
        if (t < 6)                { asm volatile("s_waitcnt vmcnt(4)" ::: "memory"); }
        else if (t == 6)          { asm volatile("s_waitcnt vmcnt(2)" ::: "memory"); }
        else                      { asm volatile("s_waitcnt vmcnt(0)" ::: "memory"); }
        __builtin_amdgcn_s_barrier();

        const __hip_bfloat16* zsp = (const __hip_bfloat16*)zs[t & 3];

        f32x4 acc[2][2];
#pragma unroll
        for (int rt = 0; rt < 2; ++rt)
#pragma unroll
            for (int ct = 0; ct < 2; ++ct) acc[rt][ct] = f32x4{0.f, 0.f, 0.f, 0.f};

        __builtin_amdgcn_s_setprio(1);
#pragma unroll
        for (int it = 0; it < 8; ++it) {
            const int js = (it * 4 + quad) ^ sw;
            bf16x8 zf0 = *(const bf16x8*)(zsp + n16 * 256 + js * 8);
            bf16x8 zf1 = *(const bf16x8*)(zsp + (n16 + 16) * 256 + js * 8);
#pragma unroll
            for (int ct = 0; ct < 2; ++ct) {
                acc[0][ct] = __builtin_amdgcn_mfma_f32_16x16x32_bf16(
                    wfrag[ct][it], zf0, acc[0][ct], 0, 0, 0);
                acc[1][ct] = __builtin_amdgcn_mfma_f32_16x16x32_bf16(
                    wfrag[ct][it], zf1, acc[1][ct], 0, 0, 0);
            }
        }
        __builtin_amdgcn_s_setprio(0);

        // ---- epilogue: zrow = rt*16+n16 ; wcols = 32w + ct*16 + quad*4 + r ----
#pragma unroll
        for (int rt = 0; rt < 2; ++rt) {
            const int row = rt * 16 + n16;
            float s = 0.f;
#pragma unroll
            for (int ct = 0; ct < 2; ++ct) {
                const int j  = 4 * wave + 2 * ct + (quad >> 1);
                const char* zp = (const char*)zsp + row * 512 + ((j ^ sw) << 4) + (quad & 1) * 8;
                uint2 zz = *(const uint2*)zp;
                float z0 = __uint_as_float(zz.x << 16);
                float z1 = __uint_as_float(zz.x & 0xffff0000u);
                float z2 = __uint_as_float(zz.y << 16);
                float z3 = __uint_as_float(zz.y & 0xffff0000u);
                s = fmaf(acc[rt][ct][0] + bias4[ct].x, z0, s);
                s = fmaf(acc[rt][ct][1] + bias4[ct].y, z1, s);
                s = fmaf(acc[rt][ct][2] + bias4[ct].z, z2, s);
                s = fmaf(acc[rt][ct][3] + bias4[ct].w, z3, s);
            }
            s += __shfl_xor(s, 16);
            s += __shfl_xor(s, 32);
            if (lane < 16) qacc[wave][t * 32 + row] = s;   // wave-private slice
        }
        // no end-of-tile barrier: buffer t&3 is next overwritten at iter t+2,
        // separated by the top barrier of iter t+1.
    }
#undef STAGE

    __syncthreads();
    // ---- block-end: reduce 8 wave partials per row, write transposed qt ----
    if (tid < 256) {
        int rg = row0 + tid;
        if (rg < N_) {
            float qv = 0.f;
#pragma unroll
            for (int w2 = 0; w2 < 8; ++w2) qv += qacc[w2][tid];
            int b = rg / L_;
            int l = rg - b * L_;
            qt[(size_t)k * QSTR + (l << 4) + b] = qv;
        }
    }
}

// -------------------- loss: coalesced gathers from transposed q, LSE, accumulate ------
__global__ __launch_bounds__(256) void loss_kernel(
    const float* __restrict__ qt, const int* __restrict__ perm, float* __restrict__ lacc)
{
    const int k = blockIdx.y + 1;                 // 1..12
    const float* qk = qt + (size_t)(k - 1) * QSTR;
    const int nval = B_ * (L_ - k);
    const int idx = blockIdx.x * 256 + threadIdx.x;

    float contrib = 0.f;
    if (idx < nval) {
        int b = idx & 15;
        int l = k + (idx >> 4);
        float f0 = qk[(l << 4) | b];
        int pl = perm[l];
        const float* qn = qk + ((size_t)pl << 4);
        float f[10];
#pragma unroll
        for (int n = 0; n < 10; ++n) f[n] = qn[(b + 15 - n) & 15];
        float m = f0;
#pragma unroll
        for (int i = 0; i < 10; ++i) m = fmaxf(m, f[i]);
        float se = expf(f0 - m), fs = f0;
#pragma unroll
        for (int i = 0; i < 10; ++i) { se += expf(f[i] - m); fs += f[i]; }
        contrib = 11.f * (m + logf(se)) - fs;
    }

    __shared__ float red[4];
#pragma unroll
    for (int off = 32; off > 0; off >>= 1) contrib += __shfl_down(contrib, off);
    const int lane = threadIdx.x & 63;
    const int wave = threadIdx.x >> 6;
    if (lane == 0) red[wave] = contrib;
    __syncthreads();
    if (threadIdx.x == 0) atomicAdd(&lacc[k - 1], red[0] + red[1] + red[2] + red[3]);
}

__global__ void finalize_loss_kernel(const float* __restrict__ lacc, float* __restrict__ out1)
{
    int k = threadIdx.x;
    if (k < KSTEPS) {
        float div = (float)((L_ - 2 * (k + 1)) * B_);
        out1[k] = lacc[k] / div;
    }
}

// -------------------- launch --------------------
extern "C" void kernel_launch(void* const* d_in, const int* in_sizes, int n_in,
                              void* d_out, int out_size, void* d_ws, size_t ws_size,
                              hipStream_t stream)
{
    const float* x     = (const float*)d_in[0];
    const float* cw    = (const float*)d_in[1];
    const float* cb    = (const float*)d_in[2];
    const float* gamma = (const float*)d_in[3];
    const float* beta  = (const float*)d_in[4];
    const float* tw    = (const float*)d_in[5];
    const float* tb    = (const float*)d_in[6];
    const int*   perm  = (const int*)d_in[7];

    float* out0 = (float*)d_out;
    float* out1 = out0 + (size_t)B_ * C_ * L_;

    char* ws = (char*)d_ws;
    __hip_bfloat16* Zb = (__hip_bfloat16*)ws;   ws += (size_t)N_ * C_ * 2;
    __hip_bfloat16* Wt = (__hip_bfloat16*)ws;   ws += (size_t)KSTEPS * C_ * C_ * 2;
    float* qt    = (float*)ws;                  ws += (size_t)KSTEPS * QSTR * 4;
    float* ssum  = (float*)ws;                  ws += C_ * 4;
    float* ssq   = (float*)ws;                  ws += C_ * 4;
    float* lacc  = (float*)ws;                  ws += 64 * 4;

    hipMemsetAsync(ssum, 0, (C_ + C_ + 64) * sizeof(float), stream);

    stats_wt_kernel<<<448, 256, 0, stream>>>(x, cw, cb, ssum, ssq, tw, Wt);

    dim3 gcv(64, 16);
    conv_norm_kernel<<<gcv, 256, 0, stream>>>(x, cw, cb, ssum, ssq, gamma, beta, Zb, out0);

    dim3 gq(128, KSTEPS);
    qmfma_kernel<<<gq, 512, 0, stream>>>(Zb, Wt, tb, qt);

    dim3 gl(128, KSTEPS);
    loss_kernel<<<gl, 256, 0, stream>>>(qt, perm, lacc);
    finalize_loss_kernel<<<1, 64, 0, stream>>>(lacc, out1);
}